// Round 7
// baseline (202.414 us; speedup 1.0000x reference)
//
#include <hip/hip_runtime.h>
#include <stdint.h>

#define NBITS  8
#define SLICE  1024
#define OUTF   512
#define INF    8192
#define TOPK   32
#define BATCHN 4096

#define ROWS    INF                        // 8192 table rows, 64 words each
#define DUMMY_B (ROWS * 64 * 4)            // BYTE offset of dummy row (fields=1)
#define TBL2_B  ((ROWS + 1) * 64 * 4)      // BYTE offset of complement table

// monotone float<->sortable-key bijection
__device__ __forceinline__ uint32_t fkey_u(uint32_t u) {
  uint32_t m = ((uint32_t)((int32_t)u >> 31)) | 0x80000000u;
  return u ^ m;
}
__device__ __forceinline__ float kfloat(uint32_t k) {
  uint32_t u = (k & 0x80000000u) ? (k ^ 0x80000000u) : ~k;
  return __uint_as_float(u);
}

// ---------------------------------------------------------------------------
// prep: pack b = (W>=0)+(Wm>=0) in {0,1,2} as 4-bit fields, 8 cols per u32.
// Word w of row r holds columns {w + 64*i}, field i.  Also writes the
// complement table (2-b), a dummy row of 1-fields, and zeroes the ticket.
// ---------------------------------------------------------------------------
__global__ __launch_bounds__(256) void prep_kernel(
    const float* __restrict__ W, const float* __restrict__ Wm,
    uint32_t* __restrict__ tbl, int* __restrict__ ticket)
{
  int tid = blockIdx.x * blockDim.x + threadIdx.x;   // 8192*64 threads
  if (tid == 0) *ticket = 0;
  int r = tid >> 6;        // row 0..8191  (= n*1024 + s)
  int w = tid & 63;        // word 0..63
  const float* wr = W  + (size_t)r * OUTF;
  const float* mr = Wm + (size_t)r * OUTF;
  uint32_t word = 0;
#pragma unroll
  for (int i = 0; i < 8; ++i) {
    int col = w + 64 * i;
    uint32_t b = (wr[col] >= 0.0f ? 1u : 0u) + (mr[col] >= 0.0f ? 1u : 0u);
    word |= b << (4 * i);
  }
  tbl[tid] = word;
  tbl[(TBL2_B / 4) + tid] = 0x22222222u - word;   // fields 2-b (b<=2, no borrow)
  if (tid < 64) tbl[(DUMMY_B / 4) + tid] = 0x11111111u;
}

// ---------------------------------------------------------------------------
// main: one block per batch row, 8 waves; wave n handles bit-slice n.
//  - seeded exact threshold search; probes placed by log-count secant
//    (Gaussian-informed), validated against the integer bracket, integer
//    upper-mid fallback.  Early exit when count==32 (exact, tie-free).
//  - fast path: prefix-scan slots; fallback: stable lowest-index-first ties.
//  - gather: 32 loads kept live simultaneously (launch_bounds(512,3) gives
//    the register budget), packed 4-bit accumulate.
//  - per-column S = 2*F - 64, cumsum over bits via LDS, store.
//  - last block (ticket) also reduces partial -> latent_group (fin fused).
// ---------------------------------------------------------------------------
__global__ __launch_bounds__(512, 3) void main_kernel(
    const float* __restrict__ latent,
    const uint32_t* __restrict__ tbl,
    float* __restrict__ out, int* __restrict__ partial,
    int* __restrict__ ticket)
{
  __shared__ __align__(16) uint32_t sel[NBITS][TOPK];   // BYTE offsets into tbl
  __shared__ float sums[NBITS][OUTF];
  __shared__ int   islast;

  const int b    = blockIdx.x;
  const int wv   = threadIdx.x >> 6;        // bit index n
  const int lane = threadIdx.x & 63;

  // ---- load 16 contiguous values, map to sortable keys, track lane max ----
  const float4* src =
      (const float4*)(latent + (size_t)b * INF + (size_t)wv * SLICE + lane * 16);
  uint32_t key[16];
  uint32_t lmax = 0u;
#pragma unroll
  for (int q = 0; q < 4; ++q) {
    float4 f = src[q];
    float vv[4] = {f.x, f.y, f.z, f.w};
#pragma unroll
    for (int t = 0; t < 4; ++t) {
      uint32_t k = fkey_u(__float_as_uint(vv[t]));
      key[4*q+t] = k;
      lmax = lmax > k ? lmax : k;
    }
  }
  // sign from key:  v>0 <=> key>0x80000000 ; v<0 <=> key<0x7FFFFFFF

  // ---- seeded bounds (valid for ANY input) --------------------------------
  // bmin = wave-min of lane maxima (>=64 elems >= bmin => T >= bmin)
  // bmax = wave-max of lane maxima (= global max >= T)
  uint32_t bmin = lmax, bmax = lmax;
#pragma unroll
  for (int d = 1; d < 64; d <<= 1) {
    uint32_t tn = (uint32_t)__shfl_xor((int)bmin, d);
    uint32_t tx = (uint32_t)__shfl_xor((int)bmax, d);
    bmin = bmin < tn ? bmin : tn;
    bmax = bmax > tx ? bmax : tx;
  }

  // ---- threshold search: log-count secant probes, exact bracket -----------
  uint32_t T = 0, midE = 0, cE = 0;
  bool fast = false;
  {
    uint32_t lo = bmin, hi = bmax;
    float flo = kfloat(lo), fhi = kfloat(hi);
    float llo = 6.0f, lhi = 0.0f;           // virtual log-counts (self-correct)
    const float l32 = 3.4657359f;           // ln(32)
    while (lo < hi) {
      float fr = (l32 - lhi) / (llo - lhi); // fraction from hi toward lo
      fr = fminf(fmaxf(fr, 0.06f), 0.94f);
      uint32_t km = fkey_u(__float_as_uint(fhi + fr * (flo - fhi)));
      uint32_t mid;
      if (km > lo && km <= hi) mid = km;    // validated value-space probe
      else { uint32_t d = hi - lo; mid = lo + (d >> 1) + (d & 1u); }
      // 4 independent count chains (break the serial add dependency)
      uint32_t c0 = 0, c1 = 0, c2 = 0, c3 = 0;
#pragma unroll
      for (int j = 0; j < 4; ++j) {
        c0 += (key[j]      >= mid) ? 1u : 0u;
        c1 += (key[j + 4]  >= mid) ? 1u : 0u;
        c2 += (key[j + 8]  >= mid) ? 1u : 0u;
        c3 += (key[j + 12] >= mid) ? 1u : 0u;
      }
      uint32_t c = (c0 + c1) + (c2 + c3);
      int cnt = 0;
#pragma unroll
      for (int bb = 0; bb < 5; ++bb)
        cnt += (int)__popcll(__ballot((c >> bb) & 1u)) << bb;
      if (cnt == TOPK) { fast = true; midE = mid; cE = c; break; }
      float lc = __logf((float)(cnt > 0 ? cnt : 1));
      if (cnt > TOPK) { lo = mid;      flo = kfloat(lo); llo = lc; }
      else            { hi = mid - 1u; fhi = kfloat(hi); lhi = lc; }
    }
    if (!fast) T = lo;
  }

  const uint32_t pbase = ((uint32_t)(wv * SLICE + lane * 16)) << 8;  // row*256
  int nzl = 0;                               // per-lane taken-nonzero count

  if (fast) {
    // ---- fast path: take set is exactly {key >= midE}, no boundary ties ---
    int sc = (int)cE;
#pragma unroll
    for (int dd = 1; dd < 64; dd <<= 1) {
      int t = __shfl_up(sc, dd);
      if (lane >= dd) sc += t;
    }
    int slot = sc - (int)cE;                 // exclusive prefix of take counts
#pragma unroll
    for (int j = 0; j < 16; ++j) {
      uint32_t kk = key[j];
      if (kk >= midE) {
        bool ispos = kk > 0x80000000u;
        bool isneg = kk < 0x7FFFFFFFu;
        uint32_t off = ispos ? (pbase + (j << 8))
                     : (isneg ? (pbase + (j << 8) + TBL2_B) : (uint32_t)DUMMY_B);
        sel[wv][slot++] = off;
        nzl += (ispos || isneg) ? 1 : 0;
      }
    }
  } else {
    // ---- fallback: stable lowest-index-first tie handling (exact) ---------
    int cgt = 0, ceq = 0;
#pragma unroll
    for (int j = 0; j < 16; ++j) { cgt += (key[j] > T); ceq += (key[j] == T); }
    int packed = (cgt << 16) | ceq;
    int sc = packed;
#pragma unroll
    for (int dd = 1; dd < 64; dd <<= 1) {
      int t = __shfl_up(sc, dd);
      if (lane >= dd) sc += t;
    }
    int tot     = __shfl(sc, 63);
    int total_g = tot >> 16;                 // # strictly greater than T
    int nties   = TOPK - total_g;            // ties to take, lowest index first
    int excl    = sc - packed;
    int posg    = excl >> 16;
    int pose    = excl & 0xFFFF;
#pragma unroll
    for (int j = 0; j < 16; ++j) {
      uint32_t kk  = key[j];
      bool isgt    = kk > T;
      bool iseq    = (kk == T);
      bool takeeq  = iseq && (pose < nties);
      bool take    = isgt || takeeq;
      bool ispos   = kk > 0x80000000u;
      bool isneg   = kk < 0x7FFFFFFFu;
      uint32_t off = ispos ? (pbase + (j << 8))
                   : (isneg ? (pbase + (j << 8) + TBL2_B) : (uint32_t)DUMMY_B);
      int slot = isgt ? posg : (total_g + pose);
      if (take) sel[wv][slot] = off;
      posg += isgt ? 1 : 0;
      pose += iseq ? 1 : 0;
      nzl  += (take && (ispos || isneg)) ? 1 : 0;
    }
  }

  // wave-sum of nzl (<=16) via bit-serial ballots
  {
    int cnz = 0;
#pragma unroll
    for (int bb = 0; bb < 5; ++bb)
      cnz += (int)__popcll(__ballot((nzl >> bb) & 1)) << bb;
    if (lane == 0) partial[wv * BATCHN + b] = cnz;
  }

  // ---- gather: 32 loads, ALL kept in flight (reg budget via l-bounds) -----
  uint32_t offr[TOPK];
  {
    const uint4* sp = (const uint4*)sel[wv];
#pragma unroll
    for (int q = 0; q < TOPK / 4; ++q) {
      uint4 e4 = sp[q];
      offr[4*q+0] = e4.x; offr[4*q+1] = e4.y;
      offr[4*q+2] = e4.z; offr[4*q+3] = e4.w;
    }
  }
  const uint32_t lb = (uint32_t)lane << 2;
  const char* tbase = (const char*)tbl;
  uint32_t wrd[TOPK];
#pragma unroll
  for (int j = 0; j < TOPK; ++j)
    wrd[j] = *(const uint32_t*)(tbase + (size_t)(offr[j] + lb));
  __builtin_amdgcn_sched_barrier(0);        // keep the gather loads batched

  uint32_t acc0 = 0, acc1 = 0, tmp = 0;
  int inch = 0;
#pragma unroll
  for (int j = 0; j < TOPK; ++j) {
    tmp += wrd[j];
    if (++inch == 7 || j == TOPK - 1) {      // <=7 words: 4-bit fields safe
      acc0 += tmp & 0x0F0F0F0Fu;
      acc1 += (tmp >> 4) & 0x0F0F0F0Fu;
      tmp = 0; inch = 0;
    }
  }

  // ---- per-column S = 2*F - 64, scaled ------------------------------------
  const float scale_n = 1.0f / (float)(1 << wv);   // 2^(6-n)*4/256 = 2^-n
#pragma unroll
  for (int i2 = 0; i2 < 4; ++i2) {
    int f0 = (int)((acc0 >> (8 * i2)) & 0xFFu);
    int f1 = (int)((acc1 >> (8 * i2)) & 0xFFu);
    sums[wv][lane + 128 * i2]      = scale_n * (float)(2 * f0 - 64);
    sums[wv][lane + 128 * i2 + 64] = scale_n * (float)(2 * f1 - 64);
  }

  __syncthreads();

  // ---- cumsum over bits, store result[n][b][col] --------------------------
  const int col = threadIdx.x;               // 0..511
  float racc = 0.0f;
  float* obase = out + 8 + (size_t)b * OUTF + col;
#pragma unroll
  for (int n2 = 0; n2 < NBITS; ++n2) {
    racc += sums[n2][col];
    obase[(size_t)n2 * BATCHN * OUTF] = racc;
  }

  // ---- last-block fin: latent_group[n] = sum_b partial[n][b] / BATCH ------
  __syncthreads();                           // all stores of this block issued
  if (threadIdx.x == 0) {
    __threadfence();                         // release partial/out stores
    int old = atomicAdd(ticket, 1);
    islast = (old == (int)gridDim.x - 1) ? 1 : 0;
  }
  __syncthreads();
  if (islast) {
    __threadfence();                         // acquire other blocks' partial
    const int* p = partial + wv * BATCHN;
    int s = 0;
#pragma unroll
    for (int k = 0; k < BATCHN / 64; ++k)
      s += p[lane + 64 * k];
#pragma unroll
    for (int d = 32; d >= 1; d >>= 1)
      s += __shfl_down(s, d);
    if (lane == 0) out[wv] = (float)s * (1.0f / (float)BATCHN);
  }
}

extern "C" void kernel_launch(void* const* d_in, const int* in_sizes, int n_in,
                              void* d_out, int out_size, void* d_ws, size_t ws_size,
                              hipStream_t stream)
{
  const float* latent = (const float*)d_in[0];
  const float* W      = (const float*)d_in[1];
  const float* Wm     = (const float*)d_in[2];
  float* out = (float*)d_out;

  int*      partial = (int*)d_ws;                          // 128 KB
  int*      ticket  = (int*)((char*)d_ws + 131072);        // 4 B (+pad)
  uint32_t* tbl     = (uint32_t*)((char*)d_ws + 131328);   // ~4.2 MB tables

  prep_kernel<<<(INF * 64) / 256, 256, 0, stream>>>(W, Wm, tbl, ticket);
  main_kernel<<<BATCHN, 512, 0, stream>>>(latent, tbl, out, partial, ticket);
}

// Round 8
// 71.017 us; speedup vs baseline: 2.8502x; 2.8502x over previous
//
#include <hip/hip_runtime.h>
#include <stdint.h>

#define NBITS  8
#define SLICE  1024
#define OUTF   512
#define INF    8192
#define TOPK   32
#define BATCHN 4096

#define ROWS    INF                        // 8192 table rows, 64 words each
#define DUMMY_B (ROWS * 64 * 4)            // BYTE offset of dummy row (fields=1)
#define TBL2_B  ((ROWS + 1) * 64 * 4)      // BYTE offset of complement table

// monotone float<->sortable-key bijection
__device__ __forceinline__ uint32_t fkey_u(uint32_t u) {
  uint32_t m = ((uint32_t)((int32_t)u >> 31)) | 0x80000000u;
  return u ^ m;
}
__device__ __forceinline__ float kfloat(uint32_t k) {
  uint32_t u = (k & 0x80000000u) ? (k ^ 0x80000000u) : ~k;
  return __uint_as_float(u);
}

// ---------------------------------------------------------------------------
// prep: pack b = (W>=0)+(Wm>=0) in {0,1,2} as 4-bit fields, 8 cols per u32.
// Word w of row r holds columns {w + 64*i}, field i.  Also writes the
// complement table (2-b) and a dummy row of 1-fields (zero contribution).
// ---------------------------------------------------------------------------
__global__ __launch_bounds__(256) void prep_kernel(
    const float* __restrict__ W, const float* __restrict__ Wm,
    uint32_t* __restrict__ tbl)
{
  int tid = blockIdx.x * blockDim.x + threadIdx.x;   // 8192*64 threads
  int r = tid >> 6;        // row 0..8191  (= n*1024 + s)
  int w = tid & 63;        // word 0..63
  const float* wr = W  + (size_t)r * OUTF;
  const float* mr = Wm + (size_t)r * OUTF;
  uint32_t word = 0;
#pragma unroll
  for (int i = 0; i < 8; ++i) {
    int col = w + 64 * i;
    uint32_t b = (wr[col] >= 0.0f ? 1u : 0u) + (mr[col] >= 0.0f ? 1u : 0u);
    word |= b << (4 * i);
  }
  tbl[tid] = word;
  tbl[(TBL2_B / 4) + tid] = 0x22222222u - word;   // fields 2-b (b<=2, no borrow)
  if (tid < 64) tbl[(DUMMY_B / 4) + tid] = 0x11111111u;
}

// ---------------------------------------------------------------------------
// main: one block per batch row, 8 waves; wave n handles bit-slice n.
// r5 structure (known 71us) + FORCED-ILP GATHER: 32 named load results pinned
// live by asm keep-alives so all 32 L2 loads are in flight at once (one
// round-trip instead of ~8 chunked ones).
// ---------------------------------------------------------------------------
__global__ __launch_bounds__(512, 4) void main_kernel(
    const float* __restrict__ latent,
    const uint32_t* __restrict__ tbl,
    float* __restrict__ out, int* __restrict__ partial)
{
  __shared__ __align__(16) uint32_t sel[NBITS][TOPK];   // BYTE offsets into tbl
  __shared__ float sums[NBITS][OUTF];

  const int b    = blockIdx.x;
  const int wv   = threadIdx.x >> 6;        // bit index n
  const int lane = threadIdx.x & 63;

  // ---- load 16 contiguous values, map to sortable keys, track lane max ----
  const float4* src =
      (const float4*)(latent + (size_t)b * INF + (size_t)wv * SLICE + lane * 16);
  uint32_t key[16];
  uint32_t lmax = 0u;
#pragma unroll
  for (int q = 0; q < 4; ++q) {
    float4 f = src[q];
    float vv[4] = {f.x, f.y, f.z, f.w};
#pragma unroll
    for (int t = 0; t < 4; ++t) {
      uint32_t k = fkey_u(__float_as_uint(vv[t]));
      key[4*q+t] = k;
      lmax = lmax > k ? lmax : k;
    }
  }
  // sign from key:  v>0 <=> key>0x80000000 ; v<0 <=> key<0x7FFFFFFF

  // ---- seeded bounds (valid for ANY input) --------------------------------
  uint32_t bmin = lmax, bmax = lmax;
#pragma unroll
  for (int d = 1; d < 64; d <<= 1) {
    uint32_t tn = (uint32_t)__shfl_xor((int)bmin, d);
    uint32_t tx = (uint32_t)__shfl_xor((int)bmax, d);
    bmin = bmin < tn ? bmin : tn;
    bmax = bmax > tx ? bmax : tx;
  }

  // ---- threshold search: value-space probes, exact bracket ----------------
  uint32_t T = 0, midE = 0, cE = 0;
  bool fast = false;
  {
    uint32_t lo = bmin, hi = bmax;
    while (lo < hi) {
      uint32_t d   = hi - lo;
      uint32_t mid = lo + (d >> 1) + (d & 1u);         // int upper-mid fallback
      float fm     = 0.5f * (kfloat(lo) + kfloat(hi)); // value-space midpoint
      uint32_t km  = fkey_u(__float_as_uint(fm));
      if (km > lo && km <= hi) mid = km;               // validated probe
      uint32_t c = 0;
#pragma unroll
      for (int j = 0; j < 16; ++j) c += (key[j] >= mid) ? 1u : 0u;
      int cnt = 0;
#pragma unroll
      for (int bb = 0; bb < 5; ++bb)
        cnt += (int)__popcll(__ballot((c >> bb) & 1u)) << bb;
      if (cnt == TOPK) { fast = true; midE = mid; cE = c; break; }
      if (cnt > TOPK) lo = mid; else hi = mid - 1u;
    }
    if (!fast) T = lo;
  }

  const uint32_t pbase = ((uint32_t)(wv * SLICE + lane * 16)) << 8;  // row*256
  int nzl = 0;                               // per-lane taken-nonzero count

  if (fast) {
    // ---- fast path: take set is exactly {key >= midE}, no boundary ties ---
    int sc = (int)cE;
#pragma unroll
    for (int dd = 1; dd < 64; dd <<= 1) {
      int t = __shfl_up(sc, dd);
      if (lane >= dd) sc += t;
    }
    int slot = sc - (int)cE;                 // exclusive prefix of take counts
#pragma unroll
    for (int j = 0; j < 16; ++j) {
      uint32_t kk = key[j];
      if (kk >= midE) {
        bool ispos = kk > 0x80000000u;
        bool isneg = kk < 0x7FFFFFFFu;
        uint32_t off = ispos ? (pbase + (j << 8))
                     : (isneg ? (pbase + (j << 8) + TBL2_B) : (uint32_t)DUMMY_B);
        sel[wv][slot++] = off;
        nzl += (ispos || isneg) ? 1 : 0;
      }
    }
  } else {
    // ---- fallback: stable lowest-index-first tie handling (exact) ---------
    int cgt = 0, ceq = 0;
#pragma unroll
    for (int j = 0; j < 16; ++j) { cgt += (key[j] > T); ceq += (key[j] == T); }
    int packed = (cgt << 16) | ceq;
    int sc = packed;
#pragma unroll
    for (int dd = 1; dd < 64; dd <<= 1) {
      int t = __shfl_up(sc, dd);
      if (lane >= dd) sc += t;
    }
    int tot     = __shfl(sc, 63);
    int total_g = tot >> 16;                 // # strictly greater than T
    int nties   = TOPK - total_g;            // ties to take, lowest index first
    int excl    = sc - packed;
    int posg    = excl >> 16;
    int pose    = excl & 0xFFFF;
#pragma unroll
    for (int j = 0; j < 16; ++j) {
      uint32_t kk  = key[j];
      bool isgt    = kk > T;
      bool iseq    = (kk == T);
      bool takeeq  = iseq && (pose < nties);
      bool take    = isgt || takeeq;
      bool ispos   = kk > 0x80000000u;
      bool isneg   = kk < 0x7FFFFFFFu;
      uint32_t off = ispos ? (pbase + (j << 8))
                   : (isneg ? (pbase + (j << 8) + TBL2_B) : (uint32_t)DUMMY_B);
      int slot = isgt ? posg : (total_g + pose);
      if (take) sel[wv][slot] = off;
      posg += isgt ? 1 : 0;
      pose += iseq ? 1 : 0;
      nzl  += (take && (ispos || isneg)) ? 1 : 0;
    }
  }

  // wave-sum of nzl (<=16) via bit-serial ballots
  {
    int cnz = 0;
#pragma unroll
    for (int bb = 0; bb < 5; ++bb)
      cnz += (int)__popcll(__ballot((nzl >> bb) & 1)) << bb;
    if (lane == 0) partial[wv * BATCHN + b] = cnz;
  }

  // ---- gather: 32 loads, pinned live -> ONE L2 round-trip -----------------
  uint32_t offr[TOPK];
  {
    const uint4* sp = (const uint4*)sel[wv];
#pragma unroll
    for (int q = 0; q < TOPK / 4; ++q) {
      uint4 e4 = sp[q];
      offr[4*q+0] = e4.x; offr[4*q+1] = e4.y;
      offr[4*q+2] = e4.z; offr[4*q+3] = e4.w;
    }
  }
  const uint32_t lb = (uint32_t)lane << 2;
  const char* tbase = (const char*)tbl;

#define LD(i) uint32_t w##i = *(const uint32_t*)(tbase + (size_t)(offr[i] + lb));
  LD(0)  LD(1)  LD(2)  LD(3)  LD(4)  LD(5)  LD(6)  LD(7)
  LD(8)  LD(9)  LD(10) LD(11) LD(12) LD(13) LD(14) LD(15)
  LD(16) LD(17) LD(18) LD(19) LD(20) LD(21) LD(22) LD(23)
  LD(24) LD(25) LD(26) LD(27) LD(28) LD(29) LD(30) LD(31)
#undef LD
  // Pin all 32 results live so regalloc cannot chunk the loads into
  // serialized load->waitcnt->consume groups (VGPR_Count is the diagnostic).
  asm volatile("" ::
    "v"(w0),"v"(w1),"v"(w2),"v"(w3),"v"(w4),"v"(w5),"v"(w6),"v"(w7),
    "v"(w8),"v"(w9),"v"(w10),"v"(w11),"v"(w12),"v"(w13),"v"(w14),"v"(w15));
  asm volatile("" ::
    "v"(w16),"v"(w17),"v"(w18),"v"(w19),"v"(w20),"v"(w21),"v"(w22),"v"(w23),
    "v"(w24),"v"(w25),"v"(w26),"v"(w27),"v"(w28),"v"(w29),"v"(w30),"v"(w31));

  // 5 independent 7-deep chunks (4-bit fields: <=7*2=14 per nibble, safe)
  uint32_t g0 = ((((w0 + w1) + (w2 + w3)) + ((w4 + w5) + w6)));
  uint32_t g1 = ((((w7 + w8) + (w9 + w10)) + ((w11 + w12) + w13)));
  uint32_t g2 = ((((w14 + w15) + (w16 + w17)) + ((w18 + w19) + w20)));
  uint32_t g3 = ((((w21 + w22) + (w23 + w24)) + ((w25 + w26) + w27)));
  uint32_t g4 = (((w28 + w29) + (w30 + w31)));
  const uint32_t M = 0x0F0F0F0Fu;
  uint32_t acc0 = (g0 & M) + (g1 & M) + (g2 & M) + (g3 & M) + (g4 & M);
  uint32_t acc1 = ((g0 >> 4) & M) + ((g1 >> 4) & M) + ((g2 >> 4) & M)
                + ((g3 >> 4) & M) + ((g4 >> 4) & M);

  // ---- per-column S = 2*F - 64, scaled ------------------------------------
  const float scale_n = 1.0f / (float)(1 << wv);   // 2^(6-n)*4/256 = 2^-n
#pragma unroll
  for (int i2 = 0; i2 < 4; ++i2) {
    int f0 = (int)((acc0 >> (8 * i2)) & 0xFFu);
    int f1 = (int)((acc1 >> (8 * i2)) & 0xFFu);
    sums[wv][lane + 128 * i2]      = scale_n * (float)(2 * f0 - 64);
    sums[wv][lane + 128 * i2 + 64] = scale_n * (float)(2 * f1 - 64);
  }

  __syncthreads();

  // ---- cumsum over bits, store result[n][b][col] --------------------------
  const int col = threadIdx.x;               // 0..511
  float racc = 0.0f;
  float* obase = out + 8 + (size_t)b * OUTF + col;
#pragma unroll
  for (int n2 = 0; n2 < NBITS; ++n2) {
    racc += sums[n2][col];
    obase[(size_t)n2 * BATCHN * OUTF] = racc;
  }
}

// ---------------------------------------------------------------------------
// finalize: latent_group[n] = (sum_b partial[n][b]) / BATCH
// ---------------------------------------------------------------------------
__global__ __launch_bounds__(512) void fin_kernel(
    const int* __restrict__ partial, float* __restrict__ out)
{
  const int wv   = threadIdx.x >> 6;
  const int lane = threadIdx.x & 63;
  const int* p = partial + wv * BATCHN;
  int s = 0;
#pragma unroll
  for (int k = 0; k < BATCHN / 64; ++k)
    s += p[lane + 64 * k];
#pragma unroll
  for (int d = 32; d >= 1; d >>= 1)
    s += __shfl_down(s, d);
  if (lane == 0) out[wv] = (float)s * (1.0f / (float)BATCHN);
}

extern "C" void kernel_launch(void* const* d_in, const int* in_sizes, int n_in,
                              void* d_out, int out_size, void* d_ws, size_t ws_size,
                              hipStream_t stream)
{
  const float* latent = (const float*)d_in[0];
  const float* W      = (const float*)d_in[1];
  const float* Wm     = (const float*)d_in[2];
  float* out = (float*)d_out;

  int*      partial = (int*)d_ws;                          // 128 KB
  uint32_t* tbl     = (uint32_t*)((char*)d_ws + 131072);   // ~4.2 MB tables

  prep_kernel<<<(INF * 64) / 256, 256, 0, stream>>>(W, Wm, tbl);
  main_kernel<<<BATCHN, 512, 0, stream>>>(latent, tbl, out, partial);
  fin_kernel<<<1, 512, 0, stream>>>(partial, out);
}

// Round 10
// 61.071 us; speedup vs baseline: 3.3144x; 1.1629x over previous
//
#include <hip/hip_runtime.h>
#include <stdint.h>

#define NBITS  8
#define SLICE  1024
#define OUTF   512
#define INF    8192
#define TOPK   32
#define BATCHN 4096

#define ROWS    INF                        // 8192 table rows, 64 words each
#define DUMMY_B (ROWS * 64 * 4)            // BYTE offset of dummy row (fields=1)
#define TBL2_B  ((ROWS + 1) * 64 * 4)      // BYTE offset of complement table

// monotone float->sortable-key bijection
__device__ __forceinline__ uint32_t fkey_u(uint32_t u) {
  uint32_t m = ((uint32_t)((int32_t)u >> 31)) | 0x80000000u;
  return u ^ m;
}

// ---- DPP cross-lane helpers (wave64, rocPRIM-standard gfx9 patterns) -------
template <int CTRL, int RMASK>
__device__ __forceinline__ int dpp_zf(int x) {    // zero-fill (for sums)
  return __builtin_amdgcn_update_dpp(0, x, CTRL, RMASK, 0xF, true);
}
template <int CTRL, int RMASK>
__device__ __forceinline__ uint32_t dpp_id(uint32_t x) {  // identity-fill
  return (uint32_t)__builtin_amdgcn_update_dpp((int)x, (int)x, CTRL, RMASK, 0xF, false);
}
// inclusive prefix sum across the full wave
__device__ __forceinline__ int wave_prefix_incl(int v) {
  v += dpp_zf<0x111, 0xF>(v);   // row_shr:1
  v += dpp_zf<0x112, 0xF>(v);   // row_shr:2
  v += dpp_zf<0x114, 0xF>(v);   // row_shr:4
  v += dpp_zf<0x118, 0xF>(v);   // row_shr:8
  v += dpp_zf<0x142, 0xA>(v);   // row_bcast:15 -> rows 1,3
  v += dpp_zf<0x143, 0xC>(v);   // row_bcast:31 -> rows 2,3
  return v;
}
__device__ __forceinline__ uint32_t wave_max_u32(uint32_t v) {
  uint32_t t;
  t = dpp_id<0x111, 0xF>(v); v = v > t ? v : t;
  t = dpp_id<0x112, 0xF>(v); v = v > t ? v : t;
  t = dpp_id<0x114, 0xF>(v); v = v > t ? v : t;
  t = dpp_id<0x118, 0xF>(v); v = v > t ? v : t;
  t = dpp_id<0x142, 0xA>(v); v = v > t ? v : t;
  t = dpp_id<0x143, 0xC>(v); v = v > t ? v : t;
  return (uint32_t)__builtin_amdgcn_readlane((int)v, 63);
}
__device__ __forceinline__ uint32_t wave_min_u32(uint32_t v) {
  uint32_t t;
  t = dpp_id<0x111, 0xF>(v); v = v < t ? v : t;
  t = dpp_id<0x112, 0xF>(v); v = v < t ? v : t;
  t = dpp_id<0x114, 0xF>(v); v = v < t ? v : t;
  t = dpp_id<0x118, 0xF>(v); v = v < t ? v : t;
  t = dpp_id<0x142, 0xA>(v); v = v < t ? v : t;
  t = dpp_id<0x143, 0xC>(v); v = v < t ? v : t;
  return (uint32_t)__builtin_amdgcn_readlane((int)v, 63);
}

// ---------------------------------------------------------------------------
// prep: pack b = (W>=0)+(Wm>=0) in {0,1,2} as 4-bit fields, 8 cols per u32.
// Word w of row r holds columns {w + 64*i}, field i.  Also writes the
// complement table (2-b) and a dummy row of 1-fields (zero contribution).
// ---------------------------------------------------------------------------
__global__ __launch_bounds__(256) void prep_kernel(
    const float* __restrict__ W, const float* __restrict__ Wm,
    uint32_t* __restrict__ tbl)
{
  int tid = blockIdx.x * blockDim.x + threadIdx.x;   // 8192*64 threads
  int r = tid >> 6;        // row 0..8191  (= n*1024 + s)
  int w = tid & 63;        // word 0..63
  const float* wr = W  + (size_t)r * OUTF;
  const float* mr = Wm + (size_t)r * OUTF;
  uint32_t word = 0;
#pragma unroll
  for (int i = 0; i < 8; ++i) {
    int col = w + 64 * i;
    uint32_t b = (wr[col] >= 0.0f ? 1u : 0u) + (mr[col] >= 0.0f ? 1u : 0u);
    word |= b << (4 * i);
  }
  tbl[tid] = word;
  tbl[(TBL2_B / 4) + tid] = 0x22222222u - word;   // fields 2-b (b<=2, no borrow)
  if (tid < 64) tbl[(DUMMY_B / 4) + tid] = 0x11111111u;
}

// ---------------------------------------------------------------------------
// main: one block per batch row, 8 waves; wave n handles bit-slice n.
//  - threshold search: seeded bounds (DPP reduces) + up to 2 LDS-histogram
//    rounds.  Keys are binned ONLY within (lo, hi]; base = count(>hi)
//    (guaranteed top-k members) is carried through the suffix tests, so
//    bin indices are always in [0,63] (r9's crash fix) and exactness holds
//    for ANY input.  Exact-edge exit when base+suffix==32 at a bin edge.
//    Residual bisection + full stable tie fallback retained.
//  - all cross-lane scans/reduces via DPP (no shfl/ballot chains).
//  - sel prefilled with DUMMY_B (defensive: logic bug => wrong answer, not
//    a wild global read).
//  - gather: 32 loads pinned live, packed 4-bit accumulate (r8-identical).
// ---------------------------------------------------------------------------
__global__ __launch_bounds__(512, 4) void main_kernel(
    const float* __restrict__ latent,
    const uint32_t* __restrict__ tbl,
    float* __restrict__ out, int* __restrict__ partial)
{
  __shared__ __align__(16) uint32_t sel[NBITS][TOPK];   // BYTE offsets into tbl
  __shared__ float sums[NBITS][OUTF];
  __shared__ int   hist[NBITS][64];

  const int b    = blockIdx.x;
  const int wv   = threadIdx.x >> 6;        // bit index n
  const int lane = threadIdx.x & 63;

  // defensive prefill: every sel slot is a valid (zero-contribution) row
  if (lane < TOPK) sel[wv][lane] = (uint32_t)DUMMY_B;

  // ---- load 16 contiguous values, map to sortable keys, track lane max ----
  const float4* src =
      (const float4*)(latent + (size_t)b * INF + (size_t)wv * SLICE + lane * 16);
  uint32_t key[16];
  uint32_t lmax = 0u;
#pragma unroll
  for (int q = 0; q < 4; ++q) {
    float4 f = src[q];
    float vv[4] = {f.x, f.y, f.z, f.w};
#pragma unroll
    for (int t = 0; t < 4; ++t) {
      uint32_t k = fkey_u(__float_as_uint(vv[t]));
      key[4*q+t] = k;
      lmax = lmax > k ? lmax : k;
    }
  }
  // sign from key:  v>0 <=> key>0x80000000 ; v<0 <=> key<0x7FFFFFFF

  // ---- seeded bounds (valid for ANY input) --------------------------------
  // lo = wave-min of lane maxima (>=64 elems >= lo => T >= lo)
  // hi = wave-max of lane maxima (= global max => count(>=hi+1)==0 < 32)
  uint32_t lo = wave_min_u32(lmax);
  uint32_t hi = wave_max_u32(lmax);

  // ---- threshold search: 2 histogram rounds + residual bisection ----------
  // Invariants: count(>=lo) >= 32 ; count(>=hi+1) < 32 ; base == count(>hi).
  uint32_t T = 0, midE = 0, cE = 0;
  int base  = 0;
  int state = 0;                            // 0 searching, 1 fast, 2 done(T)

#pragma unroll 1
  for (int round = 0; round < 2; ++round) {
    if (lo >= hi) break;
    uint32_t width = hi - lo;               // >= 1
    int bl  = 32 - __builtin_clz(width);
    int shr = bl > 6 ? bl - 6 : 0;          // (width-1)>>shr <= 63
    hist[wv][lane] = 0;
#pragma unroll
    for (int j = 0; j < 16; ++j) {
      uint32_t kk = key[j];
      if (kk > lo && (kk - lo) <= width)    // bin ONLY (lo, hi]  (crash fix)
        atomicAdd(&hist[wv][(kk - lo - 1u) >> shr], 1);
    }
    int myc = hist[wv][lane];
    int P   = wave_prefix_incl(myc);
    int tot = __builtin_amdgcn_readlane(P, 63);
    // full count(key >= edge_lane), edge_lane = lo+1+(lane<<shr):
    int suf = base + (tot - P + myc);
    unsigned long long m32 = __ballot(suf == TOPK);
    if (m32) {                              // exact top-k at a bin edge
      int l = (int)__builtin_ctzll(m32);
      midE = lo + 1u + ((uint32_t)l << shr);
      uint32_t c = 0;
#pragma unroll
      for (int j = 0; j < 16; ++j) c += (key[j] >= midE) ? 1u : 0u;
      cE = c; state = 1; break;
    }
    unsigned long long mge = __ballot(suf > TOPK);
    if (mge == 0ULL) { T = lo; state = 2; break; }   // count(>=lo+1) < 32
    int bstar = 63 - (int)__builtin_clzll(mge);      // highest edge, suf>32
    uint32_t nlo = lo + 1u + ((uint32_t)bstar << shr);
    if (bstar < 63) {
      base = __builtin_amdgcn_readlane(suf, bstar + 1);  // count(> new hi)
      hi   = lo + ((uint32_t)(bstar + 1) << shr);
    }                                        // bstar==63: hi, base unchanged
    lo = nlo;
  }

  if (state == 0) {                          // residual exact bisection
    while (lo < hi) {
      uint32_t d   = hi - lo;
      uint32_t mid = lo + (d >> 1) + (d & 1u);
      uint32_t c = 0;
#pragma unroll
      for (int j = 0; j < 16; ++j) c += (key[j] >= mid) ? 1u : 0u;
      int cnt = __builtin_amdgcn_readlane(wave_prefix_incl((int)c), 63);
      if (cnt == TOPK) { midE = mid; cE = c; state = 1; break; }
      if (cnt > TOPK) lo = mid; else hi = mid - 1u;
    }
    if (state == 0) { T = lo; state = 2; }
  }

  const uint32_t pbase = ((uint32_t)(wv * SLICE + lane * 16)) << 8;  // row*256
  int nzl = 0;                               // per-lane taken-nonzero count

  if (state == 1) {
    // ---- fast path: take set is exactly {key >= midE}, tie-free -----------
    int slot = wave_prefix_incl((int)cE) - (int)cE;   // exclusive prefix
#pragma unroll
    for (int j = 0; j < 16; ++j) {
      uint32_t kk = key[j];
      if (kk >= midE) {
        bool ispos = kk > 0x80000000u;
        bool isneg = kk < 0x7FFFFFFFu;
        uint32_t off = ispos ? (pbase + (j << 8))
                     : (isneg ? (pbase + (j << 8) + TBL2_B) : (uint32_t)DUMMY_B);
        sel[wv][slot++] = off;
        nzl += (ispos || isneg) ? 1 : 0;
      }
    }
  } else {
    // ---- fallback: stable lowest-index-first tie handling (exact) ---------
    int cgt = 0, ceq = 0;
#pragma unroll
    for (int j = 0; j < 16; ++j) { cgt += (key[j] > T); ceq += (key[j] == T); }
    int packed  = (cgt << 16) | ceq;
    int sc_incl = wave_prefix_incl(packed);
    int tot2    = __builtin_amdgcn_readlane(sc_incl, 63);
    int total_g = tot2 >> 16;                // # strictly greater than T
    int nties   = TOPK - total_g;            // ties to take, lowest index first
    int excl    = sc_incl - packed;
    int posg    = excl >> 16;
    int pose    = excl & 0xFFFF;
#pragma unroll
    for (int j = 0; j < 16; ++j) {
      uint32_t kk  = key[j];
      bool isgt    = kk > T;
      bool iseq    = (kk == T);
      bool takeeq  = iseq && (pose < nties);
      bool take    = isgt || takeeq;
      bool ispos   = kk > 0x80000000u;
      bool isneg   = kk < 0x7FFFFFFFu;
      uint32_t off = ispos ? (pbase + (j << 8))
                   : (isneg ? (pbase + (j << 8) + TBL2_B) : (uint32_t)DUMMY_B);
      int slot = isgt ? posg : (total_g + pose);
      if (take) sel[wv][slot] = off;
      posg += isgt ? 1 : 0;
      pose += iseq ? 1 : 0;
      nzl  += (take && (ispos || isneg)) ? 1 : 0;
    }
  }

  // wave-sum of nzl via DPP prefix (lane 63 holds the total)
  {
    int cnzP = wave_prefix_incl(nzl);
    if (lane == 63) partial[wv * BATCHN + b] = cnzP;
  }

  // ---- gather: 32 loads, pinned live -> one L2 round-trip -----------------
  uint32_t offr[TOPK];
  {
    const uint4* sp = (const uint4*)sel[wv];
#pragma unroll
    for (int q = 0; q < TOPK / 4; ++q) {
      uint4 e4 = sp[q];
      offr[4*q+0] = e4.x; offr[4*q+1] = e4.y;
      offr[4*q+2] = e4.z; offr[4*q+3] = e4.w;
    }
  }
  const uint32_t lb = (uint32_t)lane << 2;
  const char* tbase = (const char*)tbl;

#define LD(i) uint32_t w##i = *(const uint32_t*)(tbase + (size_t)(offr[i] + lb));
  LD(0)  LD(1)  LD(2)  LD(3)  LD(4)  LD(5)  LD(6)  LD(7)
  LD(8)  LD(9)  LD(10) LD(11) LD(12) LD(13) LD(14) LD(15)
  LD(16) LD(17) LD(18) LD(19) LD(20) LD(21) LD(22) LD(23)
  LD(24) LD(25) LD(26) LD(27) LD(28) LD(29) LD(30) LD(31)
#undef LD
  asm volatile("" ::
    "v"(w0),"v"(w1),"v"(w2),"v"(w3),"v"(w4),"v"(w5),"v"(w6),"v"(w7),
    "v"(w8),"v"(w9),"v"(w10),"v"(w11),"v"(w12),"v"(w13),"v"(w14),"v"(w15));
  asm volatile("" ::
    "v"(w16),"v"(w17),"v"(w18),"v"(w19),"v"(w20),"v"(w21),"v"(w22),"v"(w23),
    "v"(w24),"v"(w25),"v"(w26),"v"(w27),"v"(w28),"v"(w29),"v"(w30),"v"(w31));

  // 5 independent <=7-deep chunks (4-bit fields: <=7*2=14 per nibble, safe)
  uint32_t g0 = (((w0 + w1) + (w2 + w3)) + ((w4 + w5) + w6));
  uint32_t g1 = (((w7 + w8) + (w9 + w10)) + ((w11 + w12) + w13));
  uint32_t g2 = (((w14 + w15) + (w16 + w17)) + ((w18 + w19) + w20));
  uint32_t g3 = (((w21 + w22) + (w23 + w24)) + ((w25 + w26) + w27));
  uint32_t g4 = ((w28 + w29) + (w30 + w31));
  const uint32_t M = 0x0F0F0F0Fu;
  uint32_t acc0 = (g0 & M) + (g1 & M) + (g2 & M) + (g3 & M) + (g4 & M);
  uint32_t acc1 = ((g0 >> 4) & M) + ((g1 >> 4) & M) + ((g2 >> 4) & M)
                + ((g3 >> 4) & M) + ((g4 >> 4) & M);

  // ---- per-column S = 2*F - 64, scaled ------------------------------------
  const float scale_n = 1.0f / (float)(1 << wv);   // 2^(6-n)*4/256 = 2^-n
#pragma unroll
  for (int i2 = 0; i2 < 4; ++i2) {
    int f0 = (int)((acc0 >> (8 * i2)) & 0xFFu);
    int f1 = (int)((acc1 >> (8 * i2)) & 0xFFu);
    sums[wv][lane + 128 * i2]      = scale_n * (float)(2 * f0 - 64);
    sums[wv][lane + 128 * i2 + 64] = scale_n * (float)(2 * f1 - 64);
  }

  __syncthreads();

  // ---- cumsum over bits, store result[n][b][col] --------------------------
  const int col = threadIdx.x;               // 0..511
  float racc = 0.0f;
  float* obase = out + 8 + (size_t)b * OUTF + col;
#pragma unroll
  for (int n2 = 0; n2 < NBITS; ++n2) {
    racc += sums[n2][col];
    obase[(size_t)n2 * BATCHN * OUTF] = racc;
  }
}

// ---------------------------------------------------------------------------
// finalize: latent_group[n] = (sum_b partial[n][b]) / BATCH
// ---------------------------------------------------------------------------
__global__ __launch_bounds__(512) void fin_kernel(
    const int* __restrict__ partial, float* __restrict__ out)
{
  const int wv   = threadIdx.x >> 6;
  const int lane = threadIdx.x & 63;
  const int* p = partial + wv * BATCHN;
  int s = 0;
#pragma unroll
  for (int k = 0; k < BATCHN / 64; ++k)
    s += p[lane + 64 * k];
#pragma unroll
  for (int d = 32; d >= 1; d >>= 1)
    s += __shfl_down(s, d);
  if (lane == 0) out[wv] = (float)s * (1.0f / (float)BATCHN);
}

extern "C" void kernel_launch(void* const* d_in, const int* in_sizes, int n_in,
                              void* d_out, int out_size, void* d_ws, size_t ws_size,
                              hipStream_t stream)
{
  const float* latent = (const float*)d_in[0];
  const float* W      = (const float*)d_in[1];
  const float* Wm     = (const float*)d_in[2];
  float* out = (float*)d_out;

  int*      partial = (int*)d_ws;                          // 128 KB
  uint32_t* tbl     = (uint32_t*)((char*)d_ws + 131072);   // ~4.2 MB tables

  prep_kernel<<<(INF * 64) / 256, 256, 0, stream>>>(W, Wm, tbl);
  main_kernel<<<BATCHN, 512, 0, stream>>>(latent, tbl, out, partial);
  fin_kernel<<<1, 512, 0, stream>>>(partial, out);
}

// Round 11
// 56.030 us; speedup vs baseline: 3.6126x; 1.0900x over previous
//
#include <hip/hip_runtime.h>
#include <stdint.h>

#define NBITS  8
#define SLICE  1024
#define OUTF   512
#define INF    8192
#define TOPK   32
#define BATCHN 4096

#define ROWS    INF                        // 8192 table rows, 64 words each
#define DUMMY_B (ROWS * 64 * 4)            // BYTE offset of dummy row (fields=1)
#define TBL2_B  ((ROWS + 1) * 64 * 4)      // BYTE offset of complement table

// monotone float->sortable-key bijection
__device__ __forceinline__ uint32_t fkey_u(uint32_t u) {
  uint32_t m = ((uint32_t)((int32_t)u >> 31)) | 0x80000000u;
  return u ^ m;
}

// ---- DPP cross-lane helpers (wave64, rocPRIM-standard gfx9 patterns) -------
template <int CTRL, int RMASK>
__device__ __forceinline__ int dpp_zf(int x) {    // zero-fill (for sums)
  return __builtin_amdgcn_update_dpp(0, x, CTRL, RMASK, 0xF, true);
}
template <int CTRL, int RMASK>
__device__ __forceinline__ uint32_t dpp_id(uint32_t x) {  // identity-fill
  return (uint32_t)__builtin_amdgcn_update_dpp((int)x, (int)x, CTRL, RMASK, 0xF, false);
}
// inclusive prefix sum across the full wave
__device__ __forceinline__ int wave_prefix_incl(int v) {
  v += dpp_zf<0x111, 0xF>(v);   // row_shr:1
  v += dpp_zf<0x112, 0xF>(v);   // row_shr:2
  v += dpp_zf<0x114, 0xF>(v);   // row_shr:4
  v += dpp_zf<0x118, 0xF>(v);   // row_shr:8
  v += dpp_zf<0x142, 0xA>(v);   // row_bcast:15 -> rows 1,3
  v += dpp_zf<0x143, 0xC>(v);   // row_bcast:31 -> rows 2,3
  return v;
}
__device__ __forceinline__ uint32_t wave_max_u32(uint32_t v) {
  uint32_t t;
  t = dpp_id<0x111, 0xF>(v); v = v > t ? v : t;
  t = dpp_id<0x112, 0xF>(v); v = v > t ? v : t;
  t = dpp_id<0x114, 0xF>(v); v = v > t ? v : t;
  t = dpp_id<0x118, 0xF>(v); v = v > t ? v : t;
  t = dpp_id<0x142, 0xA>(v); v = v > t ? v : t;
  t = dpp_id<0x143, 0xC>(v); v = v > t ? v : t;
  return (uint32_t)__builtin_amdgcn_readlane((int)v, 63);
}
__device__ __forceinline__ uint32_t wave_min_u32(uint32_t v) {
  uint32_t t;
  t = dpp_id<0x111, 0xF>(v); v = v < t ? v : t;
  t = dpp_id<0x112, 0xF>(v); v = v < t ? v : t;
  t = dpp_id<0x114, 0xF>(v); v = v < t ? v : t;
  t = dpp_id<0x118, 0xF>(v); v = v < t ? v : t;
  t = dpp_id<0x142, 0xA>(v); v = v < t ? v : t;
  t = dpp_id<0x143, 0xC>(v); v = v < t ? v : t;
  return (uint32_t)__builtin_amdgcn_readlane((int)v, 63);
}

// ---------------------------------------------------------------------------
// prep: pack b = (W>=0)+(Wm>=0) in {0,1,2} as 4-bit fields, 8 cols per u32.
// Word w of row r holds columns {w + 64*i}, field i.  Also writes the
// complement table (2-b) and a dummy row of 1-fields (zero contribution).
// ---------------------------------------------------------------------------
__global__ __launch_bounds__(256) void prep_kernel(
    const float* __restrict__ W, const float* __restrict__ Wm,
    uint32_t* __restrict__ tbl)
{
  int tid = blockIdx.x * blockDim.x + threadIdx.x;   // 8192*64 threads
  int r = tid >> 6;        // row 0..8191  (= n*1024 + s)
  int w = tid & 63;        // word 0..63
  const float* wr = W  + (size_t)r * OUTF;
  const float* mr = Wm + (size_t)r * OUTF;
  uint32_t word = 0;
#pragma unroll
  for (int i = 0; i < 8; ++i) {
    int col = w + 64 * i;
    uint32_t b = (wr[col] >= 0.0f ? 1u : 0u) + (mr[col] >= 0.0f ? 1u : 0u);
    word |= b << (4 * i);
  }
  tbl[tid] = word;
  tbl[(TBL2_B / 4) + tid] = 0x22222222u - word;   // fields 2-b (b<=2, no borrow)
  if (tid < 64) tbl[(DUMMY_B / 4) + tid] = 0x11111111u;
}

// ---------------------------------------------------------------------------
// main: one block per batch row, 8 waves; wave n handles bit-slice n.
//  - threshold search: seeded bounds (DPP) + up to 2 LDS-histogram rounds
//    (r10-exact), residual bisection + stable tie fallback retained.
//  - NEW: positive-threshold fast path (midE > +0 key): selection is 1 cmp +
//    store per key, partial = 32 constant.  General path kept for exactness.
//  - NEW: gather uses readfirstlane'd wave-uniform row offsets -> SGPR-based
//    addressing (saves ~2 VALU per load).
// ---------------------------------------------------------------------------
__global__ __launch_bounds__(512, 4) void main_kernel(
    const float* __restrict__ latent,
    const uint32_t* __restrict__ tbl,
    float* __restrict__ out, int* __restrict__ partial)
{
  __shared__ __align__(16) uint32_t sel[NBITS][TOPK];   // BYTE offsets into tbl
  __shared__ float sums[NBITS][OUTF];
  __shared__ int   hist[NBITS][64];

  const int b    = blockIdx.x;
  const int wv   = threadIdx.x >> 6;        // bit index n
  const int lane = threadIdx.x & 63;

  // defensive prefill: every sel slot is a valid (zero-contribution) row
  if (lane < TOPK) sel[wv][lane] = (uint32_t)DUMMY_B;

  // ---- load 16 contiguous values, map to sortable keys, track lane max ----
  const float4* src =
      (const float4*)(latent + (size_t)b * INF + (size_t)wv * SLICE + lane * 16);
  uint32_t key[16];
  uint32_t lmax = 0u;
#pragma unroll
  for (int q = 0; q < 4; ++q) {
    float4 f = src[q];
    float vv[4] = {f.x, f.y, f.z, f.w};
#pragma unroll
    for (int t = 0; t < 4; ++t) {
      uint32_t k = fkey_u(__float_as_uint(vv[t]));
      key[4*q+t] = k;
      lmax = lmax > k ? lmax : k;
    }
  }
  // sign from key:  v>0 <=> key>0x80000000 ; v<0 <=> key<0x7FFFFFFF

  // ---- seeded bounds (valid for ANY input) --------------------------------
  uint32_t lo = wave_min_u32(lmax);
  uint32_t hi = wave_max_u32(lmax);

  // ---- threshold search: 2 histogram rounds + residual bisection ----------
  // Invariants: count(>=lo) >= 32 ; count(>=hi+1) < 32 ; base == count(>hi).
  uint32_t T = 0, midE = 0, cE = 0;
  int base  = 0;
  int state = 0;                            // 0 searching, 1 fast, 2 done(T)

#pragma unroll 1
  for (int round = 0; round < 2; ++round) {
    if (lo >= hi) break;
    uint32_t width = hi - lo;               // >= 1
    int bl  = 32 - __builtin_clz(width);
    int shr = bl > 6 ? bl - 6 : 0;          // (width-1)>>shr <= 63
    hist[wv][lane] = 0;
#pragma unroll
    for (int j = 0; j < 16; ++j) {
      uint32_t d1 = key[j] - lo - 1u;       // underflows for key<=lo
      if (d1 < width)                       // bin ONLY (lo, hi]
        atomicAdd(&hist[wv][d1 >> shr], 1);
    }
    int myc = hist[wv][lane];
    int P   = wave_prefix_incl(myc);
    int tot = __builtin_amdgcn_readlane(P, 63);
    // full count(key >= edge_lane), edge_lane = lo+1+(lane<<shr):
    int suf = base + (tot - P + myc);
    unsigned long long m32 = __ballot(suf == TOPK);
    if (m32) {                              // exact top-k at a bin edge
      int l = (int)__builtin_ctzll(m32);
      midE = lo + 1u + ((uint32_t)l << shr);
      uint32_t c = 0;
#pragma unroll
      for (int j = 0; j < 16; ++j) c += (key[j] >= midE) ? 1u : 0u;
      cE = c; state = 1; break;
    }
    unsigned long long mge = __ballot(suf > TOPK);
    if (mge == 0ULL) { T = lo; state = 2; break; }   // count(>=lo+1) < 32
    int bstar = 63 - (int)__builtin_clzll(mge);      // highest edge, suf>32
    uint32_t nlo = lo + 1u + ((uint32_t)bstar << shr);
    if (bstar < 63) {
      base = __builtin_amdgcn_readlane(suf, bstar + 1);  // count(> new hi)
      hi   = lo + ((uint32_t)(bstar + 1) << shr);
    }                                        // bstar==63: hi, base unchanged
    lo = nlo;
  }

  if (state == 0) {                          // residual exact bisection
    while (lo < hi) {
      uint32_t d   = hi - lo;
      uint32_t mid = lo + (d >> 1) + (d & 1u);
      uint32_t c = 0;
#pragma unroll
      for (int j = 0; j < 16; ++j) c += (key[j] >= mid) ? 1u : 0u;
      int cnt = __builtin_amdgcn_readlane(wave_prefix_incl((int)c), 63);
      if (cnt == TOPK) { midE = mid; cE = c; state = 1; break; }
      if (cnt > TOPK) lo = mid; else hi = mid - 1u;
    }
    if (state == 0) { T = lo; state = 2; }
  }

  const uint32_t pbase = ((uint32_t)(wv * SLICE + lane * 16)) << 8;  // row*256

  if (state == 1 && midE > 0x80000000u) {
    // ---- fast-fast path: tie-free AND all taken keys strictly positive ----
    int slot = wave_prefix_incl((int)cE) - (int)cE;   // exclusive prefix
#pragma unroll
    for (int j = 0; j < 16; ++j) {
      if (key[j] >= midE) sel[wv][slot++] = pbase + (j << 8);
    }
    if (lane == 0) partial[wv * BATCHN + b] = TOPK;   // all 32 nonzero
  } else if (state == 1) {
    // ---- fast path with sign folding (tie-free) ----------------------------
    int nzl = 0;
    int slot = wave_prefix_incl((int)cE) - (int)cE;
#pragma unroll
    for (int j = 0; j < 16; ++j) {
      uint32_t kk = key[j];
      if (kk >= midE) {
        bool ispos = kk > 0x80000000u;
        bool isneg = kk < 0x7FFFFFFFu;
        uint32_t off = ispos ? (pbase + (j << 8))
                     : (isneg ? (pbase + (j << 8) + TBL2_B) : (uint32_t)DUMMY_B);
        sel[wv][slot++] = off;
        nzl += (ispos || isneg) ? 1 : 0;
      }
    }
    int cnzP = wave_prefix_incl(nzl);
    if (lane == 63) partial[wv * BATCHN + b] = cnzP;
  } else {
    // ---- fallback: stable lowest-index-first tie handling (exact) ---------
    int nzl = 0;
    int cgt = 0, ceq = 0;
#pragma unroll
    for (int j = 0; j < 16; ++j) { cgt += (key[j] > T); ceq += (key[j] == T); }
    int packed  = (cgt << 16) | ceq;
    int sc_incl = wave_prefix_incl(packed);
    int tot2    = __builtin_amdgcn_readlane(sc_incl, 63);
    int total_g = tot2 >> 16;                // # strictly greater than T
    int nties   = TOPK - total_g;            // ties to take, lowest index first
    int excl    = sc_incl - packed;
    int posg    = excl >> 16;
    int pose    = excl & 0xFFFF;
#pragma unroll
    for (int j = 0; j < 16; ++j) {
      uint32_t kk  = key[j];
      bool isgt    = kk > T;
      bool iseq    = (kk == T);
      bool takeeq  = iseq && (pose < nties);
      bool take    = isgt || takeeq;
      bool ispos   = kk > 0x80000000u;
      bool isneg   = kk < 0x7FFFFFFFu;
      uint32_t off = ispos ? (pbase + (j << 8))
                   : (isneg ? (pbase + (j << 8) + TBL2_B) : (uint32_t)DUMMY_B);
      int slot = isgt ? posg : (total_g + pose);
      if (take) sel[wv][slot] = off;
      posg += isgt ? 1 : 0;
      pose += iseq ? 1 : 0;
      nzl  += (take && (ispos || isneg)) ? 1 : 0;
    }
    int cnzP = wave_prefix_incl(nzl);
    if (lane == 63) partial[wv * BATCHN + b] = cnzP;
  }

  // ---- gather: 32 loads, wave-uniform offsets -> SGPR addressing ----------
  uint32_t offr[TOPK];
  {
    const uint4* sp = (const uint4*)sel[wv];
#pragma unroll
    for (int q = 0; q < TOPK / 4; ++q) {
      uint4 e4 = sp[q];
      offr[4*q+0] = e4.x; offr[4*q+1] = e4.y;
      offr[4*q+2] = e4.z; offr[4*q+3] = e4.w;
    }
  }
  const uint32_t lb = (uint32_t)lane << 2;
  const char* tbase = (const char*)tbl;

#define LD(i)                                                                  \
  uint32_t w##i;                                                               \
  {                                                                            \
    uint32_t ro = (uint32_t)__builtin_amdgcn_readfirstlane((int)offr[i]);      \
    w##i = *(const uint32_t*)(tbase + (size_t)ro + lb);                        \
  }
  LD(0)  LD(1)  LD(2)  LD(3)  LD(4)  LD(5)  LD(6)  LD(7)
  LD(8)  LD(9)  LD(10) LD(11) LD(12) LD(13) LD(14) LD(15)
  LD(16) LD(17) LD(18) LD(19) LD(20) LD(21) LD(22) LD(23)
  LD(24) LD(25) LD(26) LD(27) LD(28) LD(29) LD(30) LD(31)
#undef LD
  asm volatile("" ::
    "v"(w0),"v"(w1),"v"(w2),"v"(w3),"v"(w4),"v"(w5),"v"(w6),"v"(w7),
    "v"(w8),"v"(w9),"v"(w10),"v"(w11),"v"(w12),"v"(w13),"v"(w14),"v"(w15));
  asm volatile("" ::
    "v"(w16),"v"(w17),"v"(w18),"v"(w19),"v"(w20),"v"(w21),"v"(w22),"v"(w23),
    "v"(w24),"v"(w25),"v"(w26),"v"(w27),"v"(w28),"v"(w29),"v"(w30),"v"(w31));

  // 5 independent <=7-deep chunks (4-bit fields: <=7*2=14 per nibble, safe)
  uint32_t g0 = (((w0 + w1) + (w2 + w3)) + ((w4 + w5) + w6));
  uint32_t g1 = (((w7 + w8) + (w9 + w10)) + ((w11 + w12) + w13));
  uint32_t g2 = (((w14 + w15) + (w16 + w17)) + ((w18 + w19) + w20));
  uint32_t g3 = (((w21 + w22) + (w23 + w24)) + ((w25 + w26) + w27));
  uint32_t g4 = ((w28 + w29) + (w30 + w31));
  const uint32_t M = 0x0F0F0F0Fu;
  uint32_t acc0 = (g0 & M) + (g1 & M) + (g2 & M) + (g3 & M) + (g4 & M);
  uint32_t acc1 = ((g0 >> 4) & M) + ((g1 >> 4) & M) + ((g2 >> 4) & M)
                + ((g3 >> 4) & M) + ((g4 >> 4) & M);

  // ---- per-column S = 2*F - 64, scaled ------------------------------------
  const float scale_n = 1.0f / (float)(1 << wv);   // 2^(6-n)*4/256 = 2^-n
#pragma unroll
  for (int i2 = 0; i2 < 4; ++i2) {
    int f0 = (int)((acc0 >> (8 * i2)) & 0xFFu);
    int f1 = (int)((acc1 >> (8 * i2)) & 0xFFu);
    sums[wv][lane + 128 * i2]      = scale_n * (float)(2 * f0 - 64);
    sums[wv][lane + 128 * i2 + 64] = scale_n * (float)(2 * f1 - 64);
  }

  __syncthreads();

  // ---- cumsum over bits, store result[n][b][col] --------------------------
  const int col = threadIdx.x;               // 0..511
  float racc = 0.0f;
  float* obase = out + 8 + (size_t)b * OUTF + col;
#pragma unroll
  for (int n2 = 0; n2 < NBITS; ++n2) {
    racc += sums[n2][col];
    obase[(size_t)n2 * BATCHN * OUTF] = racc;
  }
}

// ---------------------------------------------------------------------------
// finalize: latent_group[n] = (sum_b partial[n][b]) / BATCH
// ---------------------------------------------------------------------------
__global__ __launch_bounds__(512) void fin_kernel(
    const int* __restrict__ partial, float* __restrict__ out)
{
  const int wv   = threadIdx.x >> 6;
  const int lane = threadIdx.x & 63;
  const int* p = partial + wv * BATCHN;
  int s = 0;
#pragma unroll
  for (int k = 0; k < BATCHN / 64; ++k)
    s += p[lane + 64 * k];
#pragma unroll
  for (int d = 32; d >= 1; d >>= 1)
    s += __shfl_down(s, d);
  if (lane == 0) out[wv] = (float)s * (1.0f / (float)BATCHN);
}

extern "C" void kernel_launch(void* const* d_in, const int* in_sizes, int n_in,
                              void* d_out, int out_size, void* d_ws, size_t ws_size,
                              hipStream_t stream)
{
  const float* latent = (const float*)d_in[0];
  const float* W      = (const float*)d_in[1];
  const float* Wm     = (const float*)d_in[2];
  float* out = (float*)d_out;

  int*      partial = (int*)d_ws;                          // 128 KB
  uint32_t* tbl     = (uint32_t*)((char*)d_ws + 131072);   // ~4.2 MB tables

  prep_kernel<<<(INF * 64) / 256, 256, 0, stream>>>(W, Wm, tbl);
  main_kernel<<<BATCHN, 512, 0, stream>>>(latent, tbl, out, partial);
  fin_kernel<<<1, 512, 0, stream>>>(partial, out);
}